// Round 16
// baseline (78.662 us; speedup 1.0000x reference)
//
#include <hip/hip_runtime.h>
#include <hip/hip_bf16.h>
#include <cstdint>
#include <cstddef>

// Problem constants (B=4, H=16, S=4096, E=128)
#define S_LEN 4096
#define E_DIM 128
#define NROWS (4 * 16 * 4096)   // 262144 token rows
#define GRID_MAIN 1024
#define ITERS 4                 // 1024 blk x 4 waves x 16 tok x 4 = NROWS

typedef __attribute__((ext_vector_type(8))) short bh8;   // 8 bf16 MFMA frag
typedef __attribute__((ext_vector_type(4))) short s4;    // 4 bf16
typedef __attribute__((ext_vector_type(4))) float f4;
typedef unsigned short u16;

__device__ __forceinline__ u16 f2bf(float f) {
    union { float f; uint32_t u; } v; v.f = f;
    uint32_t r = v.u + 0x7FFFu + ((v.u >> 16) & 1u);
    return (u16)(r >> 16);
}
__device__ __forceinline__ short bfc(float f) {
    __hip_bfloat16 h = __float2bfloat16(f);
    return *reinterpret_cast<short*>(&h);
}
__device__ __forceinline__ float bf2f(u16 u) {
    union { uint32_t u; float f; } v; v.u = ((uint32_t)u) << 16;
    return v.f;
}

// ============================================================================
// Fused prologue (R11 verbatim, verified): block 0 = Cayley chain via MFMA;
// blocks 1..16 = interleaved cos/sin table csT[s*128+2f]={cos,sin}.
// ============================================================================
__device__ __forceinline__ bh8 ldsRow(const u16* M, int row, int c) {
    return *(const bh8*)(&M[row * 128 + ((c ^ (row & 15)) * 8)]);
}
__device__ __forceinline__ int swzIdx(int n, int m) {
    return n * 128 + (((m >> 3) ^ (n & 15)) * 8) + (m & 7);
}

__global__ __launch_bounds__(1024) void k_pro(const float* __restrict__ Sc,
        const float* __restrict__ pos, u16* __restrict__ Qb,
        float* __restrict__ csT) {
    if (blockIdx.x != 0) {
        int t = (blockIdx.x - 1) * 1024 + threadIdx.x;
        for (int e = t; e < S_LEN * 64; e += 16 * 1024) {
            int s = e >> 6, f = e & 63;
            float freq = exp2f(-0.20762050593046015f * (float)f);  // 10000^(-f/64)
            float sv, cv;
            sincosf(pos[s] * freq, &sv, &cv);
            csT[s * 128 + 2 * f]     = cv;
            csT[s * 128 + 2 * f + 1] = sv;
        }
        return;
    }
    __shared__ u16 Abf[128 * 128];
    __shared__ u16 A2bf[128 * 128];
    __shared__ u16 Y1bf[128 * 128];
    __shared__ u16 A4bf[128 * 128];

    for (int e = threadIdx.x; e < 16384; e += 1024) {
        int i = e >> 7, j = e & 127;
        float a = 0.5f * (Sc[i * 128 + j] - Sc[j * 128 + i]);
        Abf[swzIdx(i, j)] = f2bf(a);
    }
    __syncthreads();

    const int wave = threadIdx.x >> 6;
    const int lane = threadIdx.x & 63;
    const int lhi = lane >> 4, llo = lane & 15;
    const int sm = wave & 7;
    const int nh = wave >> 3;

    {   // pass 1: A2 = -RR(A,A); Y1 = A + A2
        f4 acc[4];
        #pragma unroll
        for (int t = 0; t < 4; ++t) { f4 z = {0.f,0.f,0.f,0.f}; acc[t] = z; }
        #pragma unroll
        for (int kk = 0; kk < 4; ++kk) {
            bh8 yf = ldsRow(Abf, sm * 16 + llo, kk * 4 + lhi);
            #pragma unroll
            for (int t = 0; t < 4; ++t) {
                bh8 xf = ldsRow(Abf, (nh * 4 + t) * 16 + llo, kk * 4 + lhi);
                acc[t] = __builtin_amdgcn_mfma_f32_16x16x32_bf16(xf, yf, acc[t], 0, 0, 0);
            }
        }
        __syncthreads();
        #pragma unroll
        for (int t = 0; t < 4; ++t)
            #pragma unroll
            for (int r = 0; r < 4; ++r) {
                int n = (nh * 4 + t) * 16 + lhi * 4 + r, m = sm * 16 + llo;
                float a2 = -acc[t][r];
                A2bf[swzIdx(n, m)] = f2bf(a2);
                Y1bf[swzIdx(n, m)] = f2bf(a2 + bf2f(Abf[swzIdx(n, m)]));
            }
    }
    __syncthreads();
    {   // pass 2: A4 = RR(A2,A2)
        f4 acc[4];
        #pragma unroll
        for (int t = 0; t < 4; ++t) { f4 z = {0.f,0.f,0.f,0.f}; acc[t] = z; }
        #pragma unroll
        for (int kk = 0; kk < 4; ++kk) {
            bh8 yf = ldsRow(A2bf, sm * 16 + llo, kk * 4 + lhi);
            #pragma unroll
            for (int t = 0; t < 4; ++t) {
                bh8 xf = ldsRow(A2bf, (nh * 4 + t) * 16 + llo, kk * 4 + lhi);
                acc[t] = __builtin_amdgcn_mfma_f32_16x16x32_bf16(xf, yf, acc[t], 0, 0, 0);
            }
        }
        #pragma unroll
        for (int t = 0; t < 4; ++t)
            #pragma unroll
            for (int r = 0; r < 4; ++r) {
                int n = (nh * 4 + t) * 16 + lhi * 4 + r, m = sm * 16 + llo;
                A4bf[swzIdx(n, m)] = f2bf(acc[t][r]);
            }
    }
    __syncthreads();
    {   // pass 3: Q = 2*(RR(A2,Y1) + RR(A4,Y1) + A2 - A)
        f4 acc[4];
        #pragma unroll
        for (int t = 0; t < 4; ++t) { f4 z = {0.f,0.f,0.f,0.f}; acc[t] = z; }
        #pragma unroll
        for (int kk = 0; kk < 4; ++kk) {
            bh8 yf = ldsRow(Y1bf, sm * 16 + llo, kk * 4 + lhi);
            #pragma unroll
            for (int t = 0; t < 4; ++t) {
                bh8 xf = ldsRow(A2bf, (nh * 4 + t) * 16 + llo, kk * 4 + lhi);
                acc[t] = __builtin_amdgcn_mfma_f32_16x16x32_bf16(xf, yf, acc[t], 0, 0, 0);
            }
        }
        #pragma unroll
        for (int kk = 0; kk < 4; ++kk) {
            bh8 yf = ldsRow(Y1bf, sm * 16 + llo, kk * 4 + lhi);
            #pragma unroll
            for (int t = 0; t < 4; ++t) {
                bh8 xf = ldsRow(A4bf, (nh * 4 + t) * 16 + llo, kk * 4 + lhi);
                acc[t] = __builtin_amdgcn_mfma_f32_16x16x32_bf16(xf, yf, acc[t], 0, 0, 0);
            }
        }
        #pragma unroll
        for (int t = 0; t < 4; ++t)
            #pragma unroll
            for (int r = 0; r < 4; ++r) {
                int n = (nh * 4 + t) * 16 + lhi * 4 + r, m = sm * 16 + llo;
                float q = 2.0f * (acc[t][r] + bf2f(A2bf[swzIdx(n, m)])
                                            - bf2f(Abf[swzIdx(n, m)]));
                Qb[n * 128 + m] = f2bf(q);
            }
    }
}

// ============================================================================
// One iteration. DS/iter: 8 b64 transpose-in writes + 4 b128 frag reads +
// 32 b128 Q reads + 8 b64 epi x reads = 52 (R11 had 96 incl. 32 shfl).
// Epilogue in ACC layout (R14): rotate-half fully in-register (acc[t],
// acc[t+4]); cos/sin from csT table (R2-verified indexing; L2-resident).
// bf16 scratch (R10-verified formulas, 0 conflicts, absmax unchanged).
// Plain f4 stores (64B/token segs; L2 merges). xs reloads it+2 (depth-2).
// ============================================================================
template <int IT>
__device__ __forceinline__ void iter_body(f4 (&xs)[8],
        const float* __restrict__ x, const float* __restrict__ csT,
        float* __restrict__ out, const u16* Plds, u16* myscr,
        int wbase0, int half, int c, int lhi, int llo) {
    const int wbase = wbase0 + IT * 64;
    const int m = wbase + llo;               // this lane's token (acc layout)
    const int s = m & (S_LEN - 1);

    // [1] transpose-in: xs (f32 store layout) -> bf16 scratch (R10 swizzle)
    #pragma unroll
    for (int j = 0; j < 8; ++j) {
        const int tok = 2 * j + half;
        s4 v;
        v[0] = bfc(xs[j][0]); v[1] = bfc(xs[j][1]);
        v[2] = bfc(xs[j][2]); v[3] = bfc(xs[j][3]);
        *(s4*)(&myscr[tok * 128 + (((c >> 1) ^ tok) & 15) * 8 + (c & 1) * 4]) = v;
    }
    __builtin_amdgcn_sched_barrier(0);

    // [2] MFMA: acc[t] = (x*Q^T)[tok=llo][n=t*16+lhi*4+r]; frags direct bf16
    f4 acc[8];
    #pragma unroll
    for (int t = 0; t < 8; ++t) { f4 z = {0.f, 0.f, 0.f, 0.f}; acc[t] = z; }
    #pragma unroll
    for (int kk = 0; kk < 4; ++kk) {
        const int pc = (kk * 4 + lhi) ^ llo;
        bh8 frag = *(const bh8*)(&myscr[llo * 128 + pc * 8]);
        #pragma unroll
        for (int t = 0; t < 8; ++t) {
            bh8 qfrag = *(const bh8*)(&Plds[(t * 16 + llo) * 128 + pc * 8]);
            acc[t] = __builtin_amdgcn_mfma_f32_16x16x32_bf16(qfrag, frag, acc[t], 0, 0, 0);
        }
    }
    __builtin_amdgcn_sched_barrier(0);

    // [3] epilogue in acc layout: xt = acc + x(bf16 scr); cs from table; store
    const float* csp = csT + (size_t)s * 128;
    float* orow = out + (size_t)m * E_DIM;
    #pragma unroll
    for (int t = 0; t < 4; ++t) {
        const int n0 = t * 16 + lhi * 4;
        const int q_lo = t * 2 + (lhi >> 1);
        const int sub = (lhi & 1) * 4;
        s4 xbl = *(const s4*)(&myscr[llo * 128 + ((q_lo ^ llo) & 15) * 8 + sub]);
        s4 xbh = *(const s4*)(&myscr[llo * 128 + (((q_lo + 8) ^ llo) & 15) * 8 + sub]);
        f4 cs_lo = *(const f4*)(csp + n0);       // {cos f, sin f, cos f+1, sin f+1}
        f4 cs_hi = *(const f4*)(csp + 64 + n0);
        f4 olo, ohi;
        #pragma unroll
        for (int r = 0; r < 4; ++r) {
            float xt1 = acc[t][r]     + bf2f((u16)xbl[r]);   // n = n0+r
            float xt2 = acc[t + 4][r] + bf2f((u16)xbh[r]);   // n+64
            float c1 = cs_lo[(r >> 1) * 2], s1 = cs_lo[(r >> 1) * 2 + 1];
            float c2 = cs_hi[(r >> 1) * 2], s2 = cs_hi[(r >> 1) * 2 + 1];
            olo[r] = xt1 * c1 - xt2 * s1;
            ohi[r] = xt2 * c2 + xt1 * s2;
        }
        *(f4*)(orow + n0) = olo;
        *(f4*)(orow + n0 + 64) = ohi;
    }
    __builtin_amdgcn_sched_barrier(0);

    // [4] reload xs with IT+2's x — youngest VMEM, lands during next iter
    if constexpr (IT + 2 < ITERS) {
        const float* xb = x + (size_t)(wbase + 128) * E_DIM;
        #pragma unroll
        for (int j = 0; j < 8; ++j)
            xs[j] = *(const f4*)(xb + (2 * j + half) * E_DIM + 4 * c);
    }
}

__global__ __launch_bounds__(256, 3) void k_main(const float* __restrict__ x,
        const u16* __restrict__ Qb, const float* __restrict__ csT,
        float* __restrict__ out) {
    __shared__ u16 Plds[128 * 128];      // 32 KB Q (swizzled)
    __shared__ u16 scr[4][16 * 128];     // 16 KB: per-wave 4 KB bf16 x-tile

    // stage Q once (chunk cc of row at cc ^ (row&15))
    #pragma unroll
    for (int i = 0; i < 8; ++i) {
        int chunk = i * 256 + threadIdx.x;
        int row = chunk >> 4, cc = chunk & 15;
        int pc = cc ^ (row & 15);
        bh8 v = *(const bh8*)(Qb + chunk * 8);
        *(bh8*)(&Plds[row * 128 + pc * 8]) = v;
    }

    const int wave = threadIdx.x >> 6;
    const int lane = threadIdx.x & 63;
    const int lhi = (lane >> 4) & 3, llo = lane & 15;
    const int half = lane >> 5;          // which of the 2 tokens per load inst
    const int c = lane & 31;             // 16B chunk within token row
    u16* myscr = scr[wave];

    const int wbase0 = blockIdx.x * (64 * ITERS) + wave * 16;

    // preload iters 0,1 (copy-shaped: 1KB contiguous per instruction)
    f4 xsA[8], xsB[8];
    {
        const float* xb0 = x + (size_t)wbase0 * E_DIM;
        const float* xb1 = xb0 + 64 * E_DIM;
        #pragma unroll
        for (int j = 0; j < 8; ++j)
            xsA[j] = *(const f4*)(xb0 + (2 * j + half) * E_DIM + 4 * c);
        #pragma unroll
        for (int j = 0; j < 8; ++j)
            xsB[j] = *(const f4*)(xb1 + (2 * j + half) * E_DIM + 4 * c);
    }
    __syncthreads();   // Q staged

    iter_body<0>(xsA, x, csT, out, Plds, myscr, wbase0, half, c, lhi, llo);
    iter_body<1>(xsB, x, csT, out, Plds, myscr, wbase0, half, c, lhi, llo);
    iter_body<2>(xsA, x, csT, out, Plds, myscr, wbase0, half, c, lhi, llo);
    iter_body<3>(xsB, x, csT, out, Plds, myscr, wbase0, half, c, lhi, llo);
}

extern "C" void kernel_launch(void* const* d_in, const int* in_sizes, int n_in,
                              void* d_out, int out_size, void* d_ws, size_t ws_size,
                              hipStream_t stream) {
    const float* x   = (const float*)d_in[0];
    const float* pos = (const float*)d_in[1];
    const float* Sc  = (const float*)d_in[2];
    float* out = (float*)d_out;

    char* ws = (char*)d_ws;
    u16* Qb     = (u16*)(ws);              // 32 KB bf16 Q = P - I
    float* csT  = (float*)(ws + 32768);    // 2 MB interleaved cos/sin

    k_pro<<<17, 1024, 0, stream>>>(Sc, pos, Qb, csT);
    k_main<<<GRID_MAIN, 256, 0, stream>>>(x, Qb, csT, out);
}

// Round 17
// 62.188 us; speedup vs baseline: 1.2649x; 1.2649x over previous
//
#include <hip/hip_runtime.h>
#include <hip/hip_bf16.h>
#include <cstdint>
#include <cstddef>

// Problem constants (B=4, H=16, S=4096, E=128)
#define S_LEN 4096
#define E_DIM 128
#define NROWS (4 * 16 * 4096)   // 262144 token rows
#define GRID_MAIN 512
#define ITERS 8                 // 512 blk x 4 waves x 16 tok x 8 = NROWS

typedef __attribute__((ext_vector_type(8))) short bh8;   // 8 bf16 MFMA frag
typedef __attribute__((ext_vector_type(4))) float f4;
typedef unsigned short u16;

__device__ __forceinline__ u16 f2bf(float f) {
    union { float f; uint32_t u; } v; v.f = f;
    uint32_t r = v.u + 0x7FFFu + ((v.u >> 16) & 1u);
    return (u16)(r >> 16);
}
__device__ __forceinline__ short bfc(float f) {
    __hip_bfloat16 h = __float2bfloat16(f);
    return *reinterpret_cast<short*>(&h);
}
__device__ __forceinline__ float bf2f(u16 u) {
    union { uint32_t u; float f; } v; v.u = ((uint32_t)u) << 16;
    return v.f;
}

// ============================================================================
// Fused prologue (R11 verbatim, verified): block 0 = Cayley chain via MFMA;
// blocks 1..16 = interleaved cos/sin table csT[s*128+2f]={cos,sin}.
// ============================================================================
__device__ __forceinline__ bh8 ldsRow(const u16* M, int row, int c) {
    return *(const bh8*)(&M[row * 128 + ((c ^ (row & 15)) * 8)]);
}
__device__ __forceinline__ int swzIdx(int n, int m) {
    return n * 128 + (((m >> 3) ^ (n & 15)) * 8) + (m & 7);
}

__global__ __launch_bounds__(1024) void k_pro(const float* __restrict__ Sc,
        const float* __restrict__ pos, u16* __restrict__ Qb,
        float* __restrict__ csT) {
    if (blockIdx.x != 0) {
        int t = (blockIdx.x - 1) * 1024 + threadIdx.x;
        for (int e = t; e < S_LEN * 64; e += 16 * 1024) {
            int s = e >> 6, f = e & 63;
            float freq = exp2f(-0.20762050593046015f * (float)f);  // 10000^(-f/64)
            float sv, cv;
            sincosf(pos[s] * freq, &sv, &cv);
            csT[s * 128 + 2 * f]     = cv;
            csT[s * 128 + 2 * f + 1] = sv;
        }
        return;
    }
    __shared__ u16 Abf[128 * 128];
    __shared__ u16 A2bf[128 * 128];
    __shared__ u16 Y1bf[128 * 128];
    __shared__ u16 A4bf[128 * 128];

    for (int e = threadIdx.x; e < 16384; e += 1024) {
        int i = e >> 7, j = e & 127;
        float a = 0.5f * (Sc[i * 128 + j] - Sc[j * 128 + i]);
        Abf[swzIdx(i, j)] = f2bf(a);
    }
    __syncthreads();

    const int wave = threadIdx.x >> 6;
    const int lane = threadIdx.x & 63;
    const int lhi = lane >> 4, llo = lane & 15;
    const int sm = wave & 7;
    const int nh = wave >> 3;

    {   // pass 1: A2 = -RR(A,A); Y1 = A + A2
        f4 acc[4];
        #pragma unroll
        for (int t = 0; t < 4; ++t) { f4 z = {0.f,0.f,0.f,0.f}; acc[t] = z; }
        #pragma unroll
        for (int kk = 0; kk < 4; ++kk) {
            bh8 yf = ldsRow(Abf, sm * 16 + llo, kk * 4 + lhi);
            #pragma unroll
            for (int t = 0; t < 4; ++t) {
                bh8 xf = ldsRow(Abf, (nh * 4 + t) * 16 + llo, kk * 4 + lhi);
                acc[t] = __builtin_amdgcn_mfma_f32_16x16x32_bf16(xf, yf, acc[t], 0, 0, 0);
            }
        }
        __syncthreads();
        #pragma unroll
        for (int t = 0; t < 4; ++t)
            #pragma unroll
            for (int r = 0; r < 4; ++r) {
                int n = (nh * 4 + t) * 16 + lhi * 4 + r, m = sm * 16 + llo;
                float a2 = -acc[t][r];
                A2bf[swzIdx(n, m)] = f2bf(a2);
                Y1bf[swzIdx(n, m)] = f2bf(a2 + bf2f(Abf[swzIdx(n, m)]));
            }
    }
    __syncthreads();
    {   // pass 2: A4 = RR(A2,A2)
        f4 acc[4];
        #pragma unroll
        for (int t = 0; t < 4; ++t) { f4 z = {0.f,0.f,0.f,0.f}; acc[t] = z; }
        #pragma unroll
        for (int kk = 0; kk < 4; ++kk) {
            bh8 yf = ldsRow(A2bf, sm * 16 + llo, kk * 4 + lhi);
            #pragma unroll
            for (int t = 0; t < 4; ++t) {
                bh8 xf = ldsRow(A2bf, (nh * 4 + t) * 16 + llo, kk * 4 + lhi);
                acc[t] = __builtin_amdgcn_mfma_f32_16x16x32_bf16(xf, yf, acc[t], 0, 0, 0);
            }
        }
        #pragma unroll
        for (int t = 0; t < 4; ++t)
            #pragma unroll
            for (int r = 0; r < 4; ++r) {
                int n = (nh * 4 + t) * 16 + lhi * 4 + r, m = sm * 16 + llo;
                A4bf[swzIdx(n, m)] = f2bf(acc[t][r]);
            }
    }
    __syncthreads();
    {   // pass 3: Q = 2*(RR(A2,Y1) + RR(A4,Y1) + A2 - A)
        f4 acc[4];
        #pragma unroll
        for (int t = 0; t < 4; ++t) { f4 z = {0.f,0.f,0.f,0.f}; acc[t] = z; }
        #pragma unroll
        for (int kk = 0; kk < 4; ++kk) {
            bh8 yf = ldsRow(Y1bf, sm * 16 + llo, kk * 4 + lhi);
            #pragma unroll
            for (int t = 0; t < 4; ++t) {
                bh8 xf = ldsRow(A2bf, (nh * 4 + t) * 16 + llo, kk * 4 + lhi);
                acc[t] = __builtin_amdgcn_mfma_f32_16x16x32_bf16(xf, yf, acc[t], 0, 0, 0);
            }
        }
        #pragma unroll
        for (int kk = 0; kk < 4; ++kk) {
            bh8 yf = ldsRow(Y1bf, sm * 16 + llo, kk * 4 + lhi);
            #pragma unroll
            for (int t = 0; t < 4; ++t) {
                bh8 xf = ldsRow(A4bf, (nh * 4 + t) * 16 + llo, kk * 4 + lhi);
                acc[t] = __builtin_amdgcn_mfma_f32_16x16x32_bf16(xf, yf, acc[t], 0, 0, 0);
            }
        }
        #pragma unroll
        for (int t = 0; t < 4; ++t)
            #pragma unroll
            for (int r = 0; r < 4; ++r) {
                int n = (nh * 4 + t) * 16 + lhi * 4 + r, m = sm * 16 + llo;
                float q = 2.0f * (acc[t][r] + bf2f(A2bf[swzIdx(n, m)])
                                            - bf2f(Abf[swzIdx(n, m)]));
                Qb[n * 128 + m] = f2bf(q);
            }
    }
}

// ============================================================================
// One iteration — R11 with hybrid epilogue. DS/iter = 72 (R11: 96):
//   8 transpose-in writes + 8 frag reads + 32 Q reads
//   + per-t: 2 x-reads + 2 o-writes (in place, same slots) = 16
//   + 8 os reads.  All 32 shfl_xor eliminated (rotate-half is in-register in
// acc layout: lane holds n (acc[t]) and n+64 (acc[t+4])).
// o-chunks overwrite the x-chunks they consumed (read-before-write per t,
// disjoint across t) -> transpose-out reuses scratch in place.
// cs from csT table, acc-layout scatter (R2-verified indexing, L2-resident).
// nt 1KB-contiguous stores (R11-proven). xs reloads it+2 (depth-2).
// ============================================================================
template <int IT>
__device__ __forceinline__ void iter_body(f4 (&xs)[8],
        const float* __restrict__ x, const float* __restrict__ csT,
        float* __restrict__ out, const u16* Plds, f4* scr,
        int wbase0, int half, int c, int lhi, int llo) {
    const int wbase = wbase0 + IT * 64;
    const int m = wbase + llo;               // this lane's token (acc layout)
    const int s = m & (S_LEN - 1);

    // [1] transpose-in: xs -> scratch (swizzled), read back as frags
    #pragma unroll
    for (int j = 0; j < 8; ++j) {
        int tk = 2 * j + half;
        scr[tk * 32 + (c ^ tk)] = xs[j];
    }
    bh8 frag[4];
    #pragma unroll
    for (int kk = 0; kk < 4; ++kk) {
        int ch0 = kk * 8 + lhi * 2;
        f4 v0 = scr[llo * 32 + (ch0 ^ llo)];
        f4 v1 = scr[llo * 32 + ((ch0 + 1) ^ llo)];
        bh8 a;
        #pragma unroll
        for (int e = 0; e < 4; ++e) { a[e] = bfc(v0[e]); a[4 + e] = bfc(v1[e]); }
        frag[kk] = a;
    }
    __builtin_amdgcn_sched_barrier(0);

    // [2] MFMA: acc[t] = (x*Q^T)[token=llo][n=t*16+lhi*4+r]
    f4 acc[8];
    #pragma unroll
    for (int t = 0; t < 8; ++t) { f4 z = {0.f, 0.f, 0.f, 0.f}; acc[t] = z; }
    #pragma unroll
    for (int kk = 0; kk < 4; ++kk) {
        #pragma unroll
        for (int t = 0; t < 8; ++t) {
            int pc = (kk * 4 + lhi) ^ llo;
            bh8 qfrag = *(const bh8*)(&Plds[(t * 16 + llo) * 128 + pc * 8]);
            acc[t] = __builtin_amdgcn_mfma_f32_16x16x32_bf16(qfrag, frag[kk], acc[t], 0, 0, 0);
        }
    }
    __builtin_amdgcn_sched_barrier(0);

    // [3] epilogue in acc layout: xt = acc + x(scr); rotate-half in-register;
    //     cs from table; write o back into the SAME scratch slots
    const float* csp = csT + (size_t)s * 128;
    #pragma unroll
    for (int t = 0; t < 4; ++t) {
        const int n0 = t * 16 + lhi * 4;
        const int cl = t * 4 + lhi;              // chunk of cols n0..n0+3
        f4 xlo = scr[llo * 32 + (cl ^ llo)];
        f4 xhi = scr[llo * 32 + ((16 + cl) ^ llo)];
        f4 cs_lo = *(const f4*)(csp + n0);       // {cos f, sin f, cos f+1, sin f+1}
        f4 cs_hi = *(const f4*)(csp + 64 + n0);
        f4 olo, ohi;
        #pragma unroll
        for (int r = 0; r < 4; ++r) {
            float xt1 = acc[t][r] + xlo[r];          // n = n0+r
            float xt2 = acc[t + 4][r] + xhi[r];      // n+64
            float c1 = cs_lo[(r >> 1) * 2], s1 = cs_lo[(r >> 1) * 2 + 1];
            float c2 = cs_hi[(r >> 1) * 2], s2 = cs_hi[(r >> 1) * 2 + 1];
            olo[r] = xt1 * c1 - xt2 * s1;
            ohi[r] = xt2 * c2 + xt1 * s2;
        }
        scr[llo * 32 + (cl ^ llo)] = olo;        // in-place: same slots as x
        scr[llo * 32 + ((16 + cl) ^ llo)] = ohi;
    }

    // [4] read o in store layout; nt 1KB-contiguous stores
    float* ob = out + (size_t)wbase * E_DIM;
    #pragma unroll
    for (int j = 0; j < 8; ++j) {
        int tk = 2 * j + half;
        f4 o = scr[tk * 32 + (c ^ tk)];
        __builtin_nontemporal_store(o, (f4*)(ob + (2 * j + half) * E_DIM + 4 * c));
    }
    __builtin_amdgcn_sched_barrier(0);

    // [5] reload xs with IT+2's x — youngest VMEM, lands during next iter
    if constexpr (IT + 2 < ITERS) {
        const float* xb = x + (size_t)(wbase + 128) * E_DIM;
        #pragma unroll
        for (int j = 0; j < 8; ++j)
            xs[j] = *(const f4*)(xb + (2 * j + half) * E_DIM + 4 * c);
    }
}

__global__ __launch_bounds__(256, 2) void k_main(const float* __restrict__ x,
        const u16* __restrict__ Qb, const float* __restrict__ csT,
        float* __restrict__ out) {
    __shared__ u16 Plds[128 * 128];      // 32 KB Q (swizzled)
    __shared__ f4 scratch[4][16 * 32];   // 32 KB: per-wave 16 tok x 32 chunks

    // stage Q once (chunk cc of row at cc ^ (row&15))
    #pragma unroll
    for (int i = 0; i < 8; ++i) {
        int chunk = i * 256 + threadIdx.x;
        int row = chunk >> 4, cc = chunk & 15;
        int pc = cc ^ (row & 15);
        bh8 v = *(const bh8*)(Qb + chunk * 8);
        *(bh8*)(&Plds[row * 128 + pc * 8]) = v;
    }

    const int wave = threadIdx.x >> 6;
    const int lane = threadIdx.x & 63;
    const int lhi = (lane >> 4) & 3, llo = lane & 15;
    const int half = lane >> 5;          // which of the 2 tokens per load inst
    const int c = lane & 31;             // 16B chunk within token row
    f4* scr = scratch[wave];

    const int wbase0 = blockIdx.x * 512 + wave * 16;

    // preload iters 0,1 (copy-shaped: 1KB contiguous per instruction)
    f4 xsA[8], xsB[8];
    {
        const float* xb0 = x + (size_t)wbase0 * E_DIM;
        const float* xb1 = xb0 + 64 * E_DIM;
        #pragma unroll
        for (int j = 0; j < 8; ++j)
            xsA[j] = *(const f4*)(xb0 + (2 * j + half) * E_DIM + 4 * c);
        #pragma unroll
        for (int j = 0; j < 8; ++j)
            xsB[j] = *(const f4*)(xb1 + (2 * j + half) * E_DIM + 4 * c);
    }
    __syncthreads();   // Q staged

    iter_body<0>(xsA, x, csT, out, Plds, scr, wbase0, half, c, lhi, llo);
    iter_body<1>(xsB, x, csT, out, Plds, scr, wbase0, half, c, lhi, llo);
    iter_body<2>(xsA, x, csT, out, Plds, scr, wbase0, half, c, lhi, llo);
    iter_body<3>(xsB, x, csT, out, Plds, scr, wbase0, half, c, lhi, llo);
    iter_body<4>(xsA, x, csT, out, Plds, scr, wbase0, half, c, lhi, llo);
    iter_body<5>(xsB, x, csT, out, Plds, scr, wbase0, half, c, lhi, llo);
    iter_body<6>(xsA, x, csT, out, Plds, scr, wbase0, half, c, lhi, llo);
    iter_body<7>(xsB, x, csT, out, Plds, scr, wbase0, half, c, lhi, llo);
}

extern "C" void kernel_launch(void* const* d_in, const int* in_sizes, int n_in,
                              void* d_out, int out_size, void* d_ws, size_t ws_size,
                              hipStream_t stream) {
    const float* x   = (const float*)d_in[0];
    const float* pos = (const float*)d_in[1];
    const float* Sc  = (const float*)d_in[2];
    float* out = (float*)d_out;

    char* ws = (char*)d_ws;
    u16* Qb     = (u16*)(ws);              // 32 KB bf16 Q = P - I
    float* csT  = (float*)(ws + 32768);    // 2 MB interleaved cos/sin

    k_pro<<<17, 1024, 0, stream>>>(Sc, pos, Qb, csT);
    k_main<<<GRID_MAIN, 256, 0, stream>>>(x, Qb, csT, out);
}

// Round 18
// 61.297 us; speedup vs baseline: 1.2833x; 1.0145x over previous
//
#include <hip/hip_runtime.h>
#include <hip/hip_bf16.h>
#include <cstdint>
#include <cstddef>

// Problem constants (B=4, H=16, S=4096, E=128)
#define S_LEN 4096
#define E_DIM 128
#define NROWS (4 * 16 * 4096)   // 262144 token rows
#define GRID_MAIN 512
#define ITERS 8                 // 512 blk x 4 waves x 16 tok x 8 = NROWS

typedef __attribute__((ext_vector_type(8))) short bh8;   // 8 bf16 MFMA frag
typedef __attribute__((ext_vector_type(4))) float f4;
typedef unsigned short u16;

__device__ __forceinline__ u16 f2bf(float f) {
    union { float f; uint32_t u; } v; v.f = f;
    uint32_t r = v.u + 0x7FFFu + ((v.u >> 16) & 1u);
    return (u16)(r >> 16);
}
__device__ __forceinline__ short bfc(float f) {
    __hip_bfloat16 h = __float2bfloat16(f);
    return *reinterpret_cast<short*>(&h);
}
__device__ __forceinline__ float bf2f(u16 u) {
    union { uint32_t u; float f; } v; v.u = ((uint32_t)u) << 16;
    return v.f;
}

// ============================================================================
// Fused prologue (verified R6-R16): block 0 = Cayley chain via MFMA;
// blocks 1..16 = interleaved cos/sin table csT[s*128+2f]={cos,sin}.
// ============================================================================
__device__ __forceinline__ bh8 ldsRow(const u16* M, int row, int c) {
    return *(const bh8*)(&M[row * 128 + ((c ^ (row & 15)) * 8)]);
}
__device__ __forceinline__ int swzIdx(int n, int m) {
    return n * 128 + (((m >> 3) ^ (n & 15)) * 8) + (m & 7);
}

__global__ __launch_bounds__(1024) void k_pro(const float* __restrict__ Sc,
        const float* __restrict__ pos, u16* __restrict__ Qb,
        float* __restrict__ csT) {
    if (blockIdx.x != 0) {
        int t = (blockIdx.x - 1) * 1024 + threadIdx.x;
        for (int e = t; e < S_LEN * 64; e += 16 * 1024) {
            int s = e >> 6, f = e & 63;
            float freq = exp2f(-0.20762050593046015f * (float)f);  // 10000^(-f/64)
            float sv, cv;
            sincosf(pos[s] * freq, &sv, &cv);
            csT[s * 128 + 2 * f]     = cv;
            csT[s * 128 + 2 * f + 1] = sv;
        }
        return;
    }
    __shared__ u16 Abf[128 * 128];
    __shared__ u16 A2bf[128 * 128];
    __shared__ u16 Y1bf[128 * 128];
    __shared__ u16 A4bf[128 * 128];

    for (int e = threadIdx.x; e < 16384; e += 1024) {
        int i = e >> 7, j = e & 127;
        float a = 0.5f * (Sc[i * 128 + j] - Sc[j * 128 + i]);
        Abf[swzIdx(i, j)] = f2bf(a);
    }
    __syncthreads();

    const int wave = threadIdx.x >> 6;
    const int lane = threadIdx.x & 63;
    const int lhi = lane >> 4, llo = lane & 15;
    const int sm = wave & 7;
    const int nh = wave >> 3;

    {   // pass 1: A2 = -RR(A,A); Y1 = A + A2
        f4 acc[4];
        #pragma unroll
        for (int t = 0; t < 4; ++t) { f4 z = {0.f,0.f,0.f,0.f}; acc[t] = z; }
        #pragma unroll
        for (int kk = 0; kk < 4; ++kk) {
            bh8 yf = ldsRow(Abf, sm * 16 + llo, kk * 4 + lhi);
            #pragma unroll
            for (int t = 0; t < 4; ++t) {
                bh8 xf = ldsRow(Abf, (nh * 4 + t) * 16 + llo, kk * 4 + lhi);
                acc[t] = __builtin_amdgcn_mfma_f32_16x16x32_bf16(xf, yf, acc[t], 0, 0, 0);
            }
        }
        __syncthreads();
        #pragma unroll
        for (int t = 0; t < 4; ++t)
            #pragma unroll
            for (int r = 0; r < 4; ++r) {
                int n = (nh * 4 + t) * 16 + lhi * 4 + r, m = sm * 16 + llo;
                float a2 = -acc[t][r];
                A2bf[swzIdx(n, m)] = f2bf(a2);
                Y1bf[swzIdx(n, m)] = f2bf(a2 + bf2f(Abf[swzIdx(n, m)]));
            }
    }
    __syncthreads();
    {   // pass 2: A4 = RR(A2,A2)
        f4 acc[4];
        #pragma unroll
        for (int t = 0; t < 4; ++t) { f4 z = {0.f,0.f,0.f,0.f}; acc[t] = z; }
        #pragma unroll
        for (int kk = 0; kk < 4; ++kk) {
            bh8 yf = ldsRow(A2bf, sm * 16 + llo, kk * 4 + lhi);
            #pragma unroll
            for (int t = 0; t < 4; ++t) {
                bh8 xf = ldsRow(A2bf, (nh * 4 + t) * 16 + llo, kk * 4 + lhi);
                acc[t] = __builtin_amdgcn_mfma_f32_16x16x32_bf16(xf, yf, acc[t], 0, 0, 0);
            }
        }
        #pragma unroll
        for (int t = 0; t < 4; ++t)
            #pragma unroll
            for (int r = 0; r < 4; ++r) {
                int n = (nh * 4 + t) * 16 + lhi * 4 + r, m = sm * 16 + llo;
                A4bf[swzIdx(n, m)] = f2bf(acc[t][r]);
            }
    }
    __syncthreads();
    {   // pass 3: Q = 2*(RR(A2,Y1) + RR(A4,Y1) + A2 - A)
        f4 acc[4];
        #pragma unroll
        for (int t = 0; t < 4; ++t) { f4 z = {0.f,0.f,0.f,0.f}; acc[t] = z; }
        #pragma unroll
        for (int kk = 0; kk < 4; ++kk) {
            bh8 yf = ldsRow(Y1bf, sm * 16 + llo, kk * 4 + lhi);
            #pragma unroll
            for (int t = 0; t < 4; ++t) {
                bh8 xf = ldsRow(A2bf, (nh * 4 + t) * 16 + llo, kk * 4 + lhi);
                acc[t] = __builtin_amdgcn_mfma_f32_16x16x32_bf16(xf, yf, acc[t], 0, 0, 0);
            }
        }
        #pragma unroll
        for (int kk = 0; kk < 4; ++kk) {
            bh8 yf = ldsRow(Y1bf, sm * 16 + llo, kk * 4 + lhi);
            #pragma unroll
            for (int t = 0; t < 4; ++t) {
                bh8 xf = ldsRow(A4bf, (nh * 4 + t) * 16 + llo, kk * 4 + lhi);
                acc[t] = __builtin_amdgcn_mfma_f32_16x16x32_bf16(xf, yf, acc[t], 0, 0, 0);
            }
        }
        #pragma unroll
        for (int t = 0; t < 4; ++t)
            #pragma unroll
            for (int r = 0; r < 4; ++r) {
                int n = (nh * 4 + t) * 16 + lhi * 4 + r, m = sm * 16 + llo;
                float q = 2.0f * (acc[t][r] + bf2f(A2bf[swzIdx(n, m)])
                                            - bf2f(Abf[swzIdx(n, m)]));
                Qb[n * 128 + m] = f2bf(q);
            }
    }
}

// ============================================================================
// One iteration of the copy-shaped pipeline (R11 champion, 61.4 us).
// xs holds THIS iter's x; at the end it is reloaded with it+2's x — the loads
// are the youngest VMEM of the iter and have a full iteration+ in flight.
// Stores are nontemporal (full 1KB/wave lines): stream to HBM, don't evict
// x from L3.
// ============================================================================
__device__ __forceinline__ void iter_body(int it, f4 (&xs)[8],
        const float* __restrict__ x, const float* __restrict__ csT,
        float* __restrict__ out, const u16* Plds, f4* scr,
        int wbase0, int half, int c, int lhi, int llo, float sg) {
    const int wbase = wbase0 + it * 64;

    // [0] cs loads, store layout (1KB contiguous: 2 adjacent csT rows/inst)
    f4 cs[8];
    #pragma unroll
    for (int j = 0; j < 8; ++j) {
        int s = (wbase + 2 * j + half) & (S_LEN - 1);
        cs[j] = *(const f4*)(csT + (size_t)s * 128 + 4 * c);
    }
    __builtin_amdgcn_sched_barrier(0);

    // [1] transpose-in: xs -> scratch (swizzled), read back as frags
    #pragma unroll
    for (int j = 0; j < 8; ++j) {
        int tk = 2 * j + half;
        scr[tk * 32 + (c ^ tk)] = xs[j];
    }
    bh8 frag[4];
    #pragma unroll
    for (int kk = 0; kk < 4; ++kk) {
        int ch0 = kk * 8 + lhi * 2;
        f4 v0 = scr[llo * 32 + (ch0 ^ llo)];
        f4 v1 = scr[llo * 32 + ((ch0 + 1) ^ llo)];
        bh8 a;
        #pragma unroll
        for (int e = 0; e < 4; ++e) { a[e] = bfc(v0[e]); a[4 + e] = bfc(v1[e]); }
        frag[kk] = a;
    }
    __builtin_amdgcn_sched_barrier(0);

    // [2] MFMA: acc[t] = (x*Q^T)[token=llo][n=t*16+lhi*4+r]
    f4 acc[8];
    #pragma unroll
    for (int t = 0; t < 8; ++t) { f4 z = {0.f, 0.f, 0.f, 0.f}; acc[t] = z; }
    #pragma unroll
    for (int kk = 0; kk < 4; ++kk) {
        #pragma unroll
        for (int t = 0; t < 8; ++t) {
            int pc = (kk * 4 + lhi) ^ llo;
            bh8 qfrag = *(const bh8*)(&Plds[(t * 16 + llo) * 128 + pc * 8]);
            acc[t] = __builtin_amdgcn_mfma_f32_16x16x32_bf16(qfrag, frag[kk], acc[t], 0, 0, 0);
        }
    }

    // [3] transpose-out: acc -> scratch -> store layout
    #pragma unroll
    for (int t = 0; t < 4; ++t) {
        scr[llo * 32 + ((t * 4 + lhi) ^ llo)]      = acc[t];
        scr[llo * 32 + ((16 + t * 4 + lhi) ^ llo)] = acc[t + 4];
    }
    f4 os[8];
    #pragma unroll
    for (int j = 0; j < 8; ++j) {
        int tk = 2 * j + half;
        os[j] = scr[tk * 32 + (c ^ tk)];
    }

    // [4] epilogue in store layout: xt = os + x; rotate-half via shfl_xor;
    //     nontemporal 1KB-contiguous stores
    float* ob = out + (size_t)wbase * E_DIM;
    #pragma unroll
    for (int j = 0; j < 8; ++j) {
        f4 xt, xp, o;
        #pragma unroll
        for (int e = 0; e < 4; ++e) xt[e] = os[j][e] + xs[j][e];
        #pragma unroll
        for (int e = 0; e < 4; ++e) xp[e] = __shfl_xor(xt[e], 16, 64);
        #pragma unroll
        for (int e = 0; e < 4; ++e) {
            float cv = cs[j][2 * (e >> 1)];
            float sv = cs[j][2 * (e >> 1) + 1];
            o[e] = xt[e] * cv + sg * xp[e] * sv;
        }
        __builtin_nontemporal_store(o, (f4*)(ob + (2 * j + half) * E_DIM + 4 * c));
    }
    __builtin_amdgcn_sched_barrier(0);

    // [5] reload xs with it+2's x — youngest VMEM, lands during iter it+1
    if (it + 2 < ITERS) {
        const float* xb = x + (size_t)(wbase + 128) * E_DIM;
        #pragma unroll
        for (int j = 0; j < 8; ++j)
            xs[j] = *(const f4*)(xb + (2 * j + half) * E_DIM + 4 * c);
    }
}

__global__ __launch_bounds__(256, 2) void k_main(const float* __restrict__ x,
        const u16* __restrict__ Qb, const float* __restrict__ csT,
        float* __restrict__ out) {
    __shared__ u16 Plds[128 * 128];      // 32 KB Q (swizzled)
    __shared__ f4 scratch[4][16 * 32];   // 32 KB: per-wave 16 tok x 32 chunks

    // stage Q once (chunk cc of row at cc ^ (row&15))
    #pragma unroll
    for (int i = 0; i < 8; ++i) {
        int chunk = i * 256 + threadIdx.x;
        int row = chunk >> 4, cc = chunk & 15;
        int pc = cc ^ (row & 15);
        bh8 v = *(const bh8*)(Qb + chunk * 8);
        *(bh8*)(&Plds[row * 128 + pc * 8]) = v;
    }

    const int wave = threadIdx.x >> 6;
    const int lane = threadIdx.x & 63;
    const int lhi = (lane >> 4) & 3, llo = lane & 15;
    const int half = lane >> 5;          // which of the 2 tokens per inst
    const int c = lane & 31;             // 16B chunk within token row
    f4* scr = scratch[wave];

    const int wbase0 = blockIdx.x * 512 + wave * 16;
    const float sg = (lane & 16) ? 1.0f : -1.0f;   // rotate-half sign

    // preload iter 0 -> xsA, iter 1 -> xsB (16 loads in flight immediately)
    f4 xsA[8], xsB[8];
    {
        const float* xb = x + (size_t)wbase0 * E_DIM;
        #pragma unroll
        for (int j = 0; j < 8; ++j)
            xsA[j] = *(const f4*)(xb + (2 * j + half) * E_DIM + 4 * c);
        const float* xb1 = x + (size_t)(wbase0 + 64) * E_DIM;
        #pragma unroll
        for (int j = 0; j < 8; ++j)
            xsB[j] = *(const f4*)(xb1 + (2 * j + half) * E_DIM + 4 * c);
    }
    __syncthreads();   // Q staged

    #pragma unroll 1
    for (int it2 = 0; it2 < ITERS; it2 += 2) {
        iter_body(it2,     xsA, x, csT, out, Plds, scr, wbase0, half, c, lhi, llo, sg);
        iter_body(it2 + 1, xsB, x, csT, out, Plds, scr, wbase0, half, c, lhi, llo, sg);
    }
}

extern "C" void kernel_launch(void* const* d_in, const int* in_sizes, int n_in,
                              void* d_out, int out_size, void* d_ws, size_t ws_size,
                              hipStream_t stream) {
    const float* x   = (const float*)d_in[0];
    const float* pos = (const float*)d_in[1];
    const float* Sc  = (const float*)d_in[2];
    float* out = (float*)d_out;

    char* ws = (char*)d_ws;
    u16* Qb     = (u16*)(ws);              // 32 KB bf16 Q = P - I
    float* csT  = (float*)(ws + 32768);    // 2 MB interleaved cos/sin

    k_pro<<<17, 1024, 0, stream>>>(Sc, pos, Qb, csT);
    k_main<<<GRID_MAIN, 256, 0, stream>>>(x, Qb, csT, out);
}